// Round 4
// baseline (74.958 us; speedup 1.0000x reference)
//
#include <hip/hip_runtime.h>

typedef _Float16 half2_t __attribute__((ext_vector_type(2)));
typedef __fp16   fp16v2  __attribute__((ext_vector_type(2)));

constexpr int C_ = 256;   // centers
constexpr float LOG2E = 1.4426950408889634f;

union F4H8 { float4 f4; half2_t h2[4]; float2 f2[2]; };
union H2U  { fp16v2 p; half2_t h; };

__device__ __forceinline__ half2_t pack2(float a, float b) {
    H2U u; u.p = __builtin_amdgcn_cvt_pkrtz(a, b); return u.h;
}

__device__ __forceinline__ float dot2acc(half2_t a, half2_t b, float c) {
#if __has_builtin(__builtin_amdgcn_fdot2)
    return __builtin_amdgcn_fdot2(a, b, c, false);
#else
    return c + (float)a.x * (float)b.x + (float)a.y * (float)b.y;
#endif
}

// out[m,n,d] = sum_c exp(-||x_n - c||^2) * (1/16) * W[m,c,d]
// exp(-d2)/16 = exp2(-d2*log2e - 4)
//
// Block = 256 threads = 4 waves. Each wave owns a 64-center chunk (32 pairs),
// each lane handles 2 n values. Table reads are wave-uniform LDS broadcasts:
// per center-PAIR, 4 LDS reads (b128 ctr, b128+b128+b64 of f16 weights).
// Weight dot-products use v_dot2_f32_f16 (fp32 accumulate).
// 4 chunk-partials per n combined via LDS at the end.
__global__ __launch_bounds__(256) void ensemble_rbf_kernel(
    const float* __restrict__ x,        // [N,2]
    const float* __restrict__ centers,  // [256,2]
    const float* __restrict__ weights,  // [5,256,2]
    float* __restrict__ out,            // [5,N,2]
    int N)
{
    // 24 KB: first 8 KB = packed pair table (128 pairs x 4 float4),
    // whole region reused as reduction scratch [4][128][12] floats after sync.
    __shared__ float4 smem4[1536];

    const int tid   = threadIdx.x;
    const int nl    = tid & 63;
    const int chunk = tid >> 6;

    // ---- stage packed pair table (threads 0..127, one pair each) ----
    if (tid < 128) {
        const int p = tid;
        float4 ctr = ((const float4*)centers)[p];       // c0x,c0y,c1x,c1y
        const float4* w4 = (const float4*)weights;      // [5][128] float4
        F4H8 uA, uB, uC;
        #pragma unroll
        for (int m = 0; m < 5; m++) {
            // q = { w[c0][0], w[c0][1], w[c1][0], w[c1][1] } for model m
            float4 q = w4[m * 128 + p];
            half2_t h0 = pack2(q.x, q.z);   // md = 2m   over (c0,c1)
            half2_t h1 = pack2(q.y, q.w);   // md = 2m+1 over (c0,c1)
            int j0 = 2 * m, j1 = 2 * m + 1;
            if (j0 < 4) uA.h2[j0] = h0; else if (j0 < 8) uB.h2[j0 - 4] = h0; else uC.h2[j0 - 8] = h0;
            if (j1 < 4) uA.h2[j1] = h1; else if (j1 < 8) uB.h2[j1 - 4] = h1; else uC.h2[j1 - 8] = h1;
        }
        uC.h2[2] = pack2(0.f, 0.f);
        uC.h2[3] = uC.h2[2];
        smem4[p * 4 + 0] = ctr;
        smem4[p * 4 + 1] = uA.f4;
        smem4[p * 4 + 2] = uB.f4;
        smem4[p * 4 + 3] = uC.f4;
    }
    __syncthreads();

    const int base = blockIdx.x * 128;
    const int n0 = base + nl;
    const int n1 = n0 + 64;
    const float2* x2 = (const float2*)x;
    float2 xv0 = x2[min(n0, N - 1)];
    float2 xv1 = x2[min(n1, N - 1)];

    float a0[10], a1[10];
    #pragma unroll
    for (int j = 0; j < 10; j++) { a0[j] = 0.f; a1[j] = 0.f; }

    const int pbase = chunk * 32;

    #pragma unroll 4
    for (int pp = 0; pp < 32; pp++) {
        int p = pbase + pp;                       // wave-uniform -> LDS broadcast
        float4 ctr = smem4[p * 4 + 0];
        F4H8 uA, uB;
        uA.f4 = smem4[p * 4 + 1];
        uB.f4 = smem4[p * 4 + 2];
        float2 wc = *((const float2*)&smem4[p * 4 + 3]);
        F4H8 uC; uC.f2[0] = wc;

        // rbf for (n0,n1) x (c0,c1)
        float dx, dy, d2;
        dx = xv0.x - ctr.x; dy = xv0.y - ctr.y; d2 = fmaf(dx, dx, dy * dy);
        float r00 = exp2f(fmaf(d2, -LOG2E, -4.0f));
        dx = xv0.x - ctr.z; dy = xv0.y - ctr.w; d2 = fmaf(dx, dx, dy * dy);
        float r01 = exp2f(fmaf(d2, -LOG2E, -4.0f));
        dx = xv1.x - ctr.x; dy = xv1.y - ctr.y; d2 = fmaf(dx, dx, dy * dy);
        float r10 = exp2f(fmaf(d2, -LOG2E, -4.0f));
        dx = xv1.x - ctr.z; dy = xv1.y - ctr.w; d2 = fmaf(dx, dx, dy * dy);
        float r11 = exp2f(fmaf(d2, -LOG2E, -4.0f));

        half2_t rp0 = pack2(r00, r01);
        half2_t rp1 = pack2(r10, r11);

        #pragma unroll
        for (int j = 0; j < 4; j++) {
            a0[j] = dot2acc(rp0, uA.h2[j], a0[j]);
            a1[j] = dot2acc(rp1, uA.h2[j], a1[j]);
        }
        #pragma unroll
        for (int j = 0; j < 4; j++) {
            a0[4 + j] = dot2acc(rp0, uB.h2[j], a0[4 + j]);
            a1[4 + j] = dot2acc(rp1, uB.h2[j], a1[4 + j]);
        }
        a0[8] = dot2acc(rp0, uC.h2[0], a0[8]);
        a1[8] = dot2acc(rp1, uC.h2[0], a1[8]);
        a0[9] = dot2acc(rp0, uC.h2[1], a0[9]);
        a1[9] = dot2acc(rp1, uC.h2[1], a1[9]);
    }

    // ---- combine 4 chunk-partials per n ----
    __syncthreads();    // table reads done; reuse smem as [4][128][12] floats
    float* smemf = (float*)smem4;
    {
        float* row0 = &smemf[(chunk * 128 + nl) * 12];
        ((float4*)row0)[0] = make_float4(a0[0], a0[1], a0[2], a0[3]);
        ((float4*)row0)[1] = make_float4(a0[4], a0[5], a0[6], a0[7]);
        ((float2*)row0)[4] = make_float2(a0[8], a0[9]);
        float* row1 = &smemf[(chunk * 128 + 64 + nl) * 12];
        ((float4*)row1)[0] = make_float4(a1[0], a1[1], a1[2], a1[3]);
        ((float4*)row1)[1] = make_float4(a1[4], a1[5], a1[6], a1[7]);
        ((float2*)row1)[4] = make_float2(a1[8], a1[9]);
    }
    __syncthreads();

    if (tid < 128) {
        const int n = base + tid;
        if (n < N) {
            float s[10];
            #pragma unroll
            for (int j = 0; j < 10; j++) s[j] = 0.f;
            #pragma unroll
            for (int k = 0; k < 4; k++) {
                const float* row = &smemf[(k * 128 + tid) * 12];
                float4 r0 = ((const float4*)row)[0];
                float4 r1 = ((const float4*)row)[1];
                float2 r2 = ((const float2*)row)[4];
                s[0] += r0.x; s[1] += r0.y; s[2] += r0.z; s[3] += r0.w;
                s[4] += r1.x; s[5] += r1.y; s[6] += r1.z; s[7] += r1.w;
                s[8] += r2.x; s[9] += r2.y;
            }
            float2* out2 = (float2*)out;
            #pragma unroll
            for (int m = 0; m < 5; m++) {
                out2[(size_t)m * N + n] = make_float2(s[2 * m], s[2 * m + 1]);
            }
        }
    }
}

extern "C" void kernel_launch(void* const* d_in, const int* in_sizes, int n_in,
                              void* d_out, int out_size, void* d_ws, size_t ws_size,
                              hipStream_t stream) {
    const float* x       = (const float*)d_in[0];  // [N,2]
    const float* centers = (const float*)d_in[1];  // [256,2]
    const float* weights = (const float*)d_in[2];  // [5,256,2]
    float* out = (float*)d_out;                    // [5,N,2]

    int N = in_sizes[0] / 2;
    int grid = (N + 127) / 128;   // 128 n per block
    ensemble_rbf_kernel<<<grid, 256, 0, stream>>>(x, centers, weights, out, N);
}

// Round 5
// 70.688 us; speedup vs baseline: 1.0604x; 1.0604x over previous
//
#include <hip/hip_runtime.h>

#if __has_builtin(__builtin_amdgcn_exp2f)
__device__ __forceinline__ float fast_exp2(float x) { return __builtin_amdgcn_exp2f(x); }
#else
__device__ __forceinline__ float fast_exp2(float x) { return exp2f(x); }
#endif

constexpr int C_ = 256;   // centers
constexpr int M_ = 5;     // ensemble size
constexpr float LOG2E = 1.4426950408889634f;

// out[m,n,d] = sum_c exp(-||x_n - c||^2) * sigma^2 * W[m,c,d],  sigma^2 = 1/16
// exp(-d2)/16 = exp2(-d2*log2e - 4)
//
// Block = 256 threads = 64 n  x  4 c-chunks (one wave per chunk, so the
// c index is wave-uniform -> all LDS table reads are broadcasts).
// Partial sums combined through an LDS reduction at the end.
// NOTE: A/A re-measure of the round-2 kernel (best measured, 70.6us) to
// calibrate the bench noise band — all visible profile time is harness
// fills at 82-84% HBM peak; kernel est. 4-6us by issue arithmetic.
__global__ __launch_bounds__(256) void ensemble_rbf_kernel(
    const float* __restrict__ x,        // [N,2]
    const float* __restrict__ centers,  // [256,2]
    const float* __restrict__ weights,  // [5,256,2]
    float* __restrict__ out,            // [5,N,2]
    int N)
{
    // packed table: per center c, 12 floats {cx, cy, w0..w9}, 48B row (16B aligned)
    // reused after the main loop as the reduction scratch [4][64][12]
    __shared__ float s_tab[C_ * 12];

    const int tid   = threadIdx.x;
    const int nl    = tid & 63;     // local n (lane)
    const int chunk = tid >> 6;     // wave id = c-chunk

    // ---- stage packed table: thread t fills row t ----
    {
        float2 cv = ((const float2*)centers)[tid];
        float* row = &s_tab[tid * 12];
        row[0] = cv.x;
        row[1] = cv.y;
        const float2* w2 = (const float2*)weights;   // [5][256] float2
        #pragma unroll
        for (int m = 0; m < M_; m++) {
            float2 wv = w2[m * C_ + tid];            // coalesced
            row[2 + 2 * m]     = wv.x;
            row[2 + 2 * m + 1] = wv.y;
        }
    }
    __syncthreads();

    const int n = blockIdx.x * 64 + nl;
    float2 xv = (n < N) ? ((const float2*)x)[n] : make_float2(0.f, 0.f);

    float accx[M_], accy[M_];
    #pragma unroll
    for (int m = 0; m < M_; m++) { accx[m] = 0.f; accy[m] = 0.f; }

    const float4* tab4 = (const float4*)s_tab;
    const int cbase = chunk * 64;

    #pragma unroll 8
    for (int cc = 0; cc < 64; cc++) {
        int c = cbase + cc;                 // wave-uniform -> LDS broadcast
        float4 t0 = tab4[c * 3 + 0];        // {cx, cy, w0, w1}
        float4 t1 = tab4[c * 3 + 1];        // {w2, w3, w4, w5}
        float4 t2 = tab4[c * 3 + 2];        // {w6, w7, w8, w9}

        float dx = xv.x - t0.x;
        float dy = xv.y - t0.y;
        float d2 = fmaf(dx, dx, dy * dy);
        float r  = fast_exp2(fmaf(d2, -LOG2E, -4.0f));   // exp(-d2)/16

        accx[0] = fmaf(r, t0.z, accx[0]);  accy[0] = fmaf(r, t0.w, accy[0]);
        accx[1] = fmaf(r, t1.x, accx[1]);  accy[1] = fmaf(r, t1.y, accy[1]);
        accx[2] = fmaf(r, t1.z, accx[2]);  accy[2] = fmaf(r, t1.w, accy[2]);
        accx[3] = fmaf(r, t2.x, accx[3]);  accy[3] = fmaf(r, t2.y, accy[3]);
        accx[4] = fmaf(r, t2.z, accx[4]);  accy[4] = fmaf(r, t2.w, accy[4]);
    }

    // ---- combine the 4 chunk-partials per n via LDS ----
    __syncthreads();   // everyone done reading the table
    {
        float4* slot = (float4*)&s_tab[(chunk * 64 + nl) * 12];
        slot[0] = make_float4(accx[0], accy[0], accx[1], accy[1]);
        slot[1] = make_float4(accx[2], accy[2], accx[3], accy[3]);
        slot[2] = make_float4(accx[4], accy[4], 0.f, 0.f);
    }
    __syncthreads();

    if (tid < 64 && n < N) {
        float4 s0 = make_float4(0.f, 0.f, 0.f, 0.f);
        float4 s1 = s0, s2 = s0;
        #pragma unroll
        for (int k = 0; k < 4; k++) {
            const float4* slot = (const float4*)&s_tab[(k * 64 + nl) * 12];
            float4 r0 = slot[0], r1 = slot[1], r2 = slot[2];
            s0.x += r0.x; s0.y += r0.y; s0.z += r0.z; s0.w += r0.w;
            s1.x += r1.x; s1.y += r1.y; s1.z += r1.z; s1.w += r1.w;
            s2.x += r2.x; s2.y += r2.y;
        }
        float2* out2 = (float2*)out;
        out2[(size_t)0 * N + n] = make_float2(s0.x, s0.y);
        out2[(size_t)1 * N + n] = make_float2(s0.z, s0.w);
        out2[(size_t)2 * N + n] = make_float2(s1.x, s1.y);
        out2[(size_t)3 * N + n] = make_float2(s1.z, s1.w);
        out2[(size_t)4 * N + n] = make_float2(s2.x, s2.y);
    }
}

extern "C" void kernel_launch(void* const* d_in, const int* in_sizes, int n_in,
                              void* d_out, int out_size, void* d_ws, size_t ws_size,
                              hipStream_t stream) {
    const float* x       = (const float*)d_in[0];  // [N,2]
    const float* centers = (const float*)d_in[1];  // [256,2]
    const float* weights = (const float*)d_in[2];  // [5,256,2]
    float* out = (float*)d_out;                    // [5,N,2]

    int N = in_sizes[0] / 2;
    int grid = (N + 63) / 64;   // 64 n per block
    ensemble_rbf_kernel<<<grid, 256, 0, stream>>>(x, centers, weights, out, N);
}